// Round 11
// baseline (553.531 us; speedup 1.0000x reference)
//
#include <hip/hip_runtime.h>
#include <math.h>

#define NPT 4096
#define NB 16

typedef short v8s __attribute__((ext_vector_type(8)));
typedef float v4f __attribute__((ext_vector_type(4)));

__device__ __forceinline__ float dist2e(float x, float y, float z,
                                        float cx, float cy, float cz) {
    float dx = __fsub_rn(x, cx), dy = __fsub_rn(y, cy), dz = __fsub_rn(z, cz);
    return __fadd_rn(__fadd_rn(__fmul_rn(dx, dx), __fmul_rn(dy, dy)), __fmul_rn(dz, dz));
}

__device__ __forceinline__ unsigned long long packdi(float v, int n) {
    return ((unsigned long long)__float_as_uint(v) << 32) |
           (unsigned long long)(0xFFFFFFFFu - (unsigned)n);
}

__device__ __forceinline__ unsigned short f2bf(float f) {
    unsigned u = __float_as_uint(f);
    u = u + 0x7FFFu + ((u >> 16) & 1u);
    return (unsigned short)(u >> 16);
}

// pack two f32 -> two bf16 (RNE), elem0 = a in low half
__device__ __forceinline__ unsigned pk2(float a, float b) {
    unsigned r;
    asm("v_cvt_pk_bf16_f32 %0, %1, %2" : "=v"(r) : "v"(a), "v"(b));
    return r;
}

// split (a,b) into bf16 hi pair + bf16 lo (residual) pair
__device__ __forceinline__ uint2 split2(float a, float b) {
    unsigned h = pk2(a, b);
    float ra = __uint_as_float(h << 16);
    float rb = __uint_as_float(h & 0xFFFF0000u);
    unsigned l = pk2(a - ra, b - rb);
    return make_uint2(h, l);
}

// raw barriers with compiler-only memory fences (no extra instructions):
// bare s_barrier is NOT a compiler fence; pin LDS op ordering explicitly.
__device__ __forceinline__ void barrier_plain() {
    asm volatile("" ::: "memory");
    __builtin_amdgcn_s_barrier();
    asm volatile("" ::: "memory");
}
__device__ __forceinline__ void barrier_lgkm() {
    asm volatile("s_waitcnt lgkmcnt(0)" ::: "memory");
    __builtin_amdgcn_s_barrier();
    asm volatile("" ::: "memory");
}

// BN+relu on 8 channels x 4 n held in regs
__device__ __forceinline__ void bn8(v4f* xv, const float* __restrict__ scl,
                                    const float* __restrict__ sft, int base) {
    const v4f s0 = *(const v4f*)(scl + base);
    const v4f s1 = *(const v4f*)(scl + base + 4);
    const v4f f0 = *(const v4f*)(sft + base);
    const v4f f1 = *(const v4f*)(sft + base + 4);
    #pragma unroll
    for (int i = 0; i < 8; ++i) {
        const float si = (i < 4) ? s0[i] : s1[i - 4];
        const float fi = (i < 4) ? f0[i] : f1[i - 4];
        #pragma unroll
        for (int j = 0; j < 4; ++j)
            xv[i][j] = fmaxf(fmaf(xv[i][j], si, fi), 0.f);
    }
}

// DPP wave64 max helpers (VALU-only reduce; result valid in lane 63)
template <int CTRL>
__device__ __forceinline__ float dpp_maxf(float v) {
    int o = __builtin_amdgcn_update_dpp(__float_as_int(v), __float_as_int(v),
                                        CTRL, 0xF, 0xF, false);
    return fmaxf(v, __int_as_float(o));
}
template <int CTRL>
__device__ __forceinline__ unsigned dpp_maxu(unsigned v) {
    unsigned o = (unsigned)__builtin_amdgcn_update_dpp((int)v, (int)v,
                                                       CTRL, 0xF, 0xF, false);
    return v > o ? v : o;
}

// ---------------- FPS segment: 256 threads, 16 register points per thread -----
__device__ void fps_seg(const float* __restrict__ xyz, int b, int it0, int it1,
                        int* __restrict__ inds_i, float* __restrict__ inds_f,
                        float* __restrict__ dws, int* __restrict__ farws,
                        char* scr) {
    unsigned long long (*s_red)[4] = (unsigned long long (*)[4])scr;
    const int t = threadIdx.x;
    const int lane = t & 63, wid = t >> 6;
    const float* pb = xyz + (size_t)b * NPT * 3;
    float px[16], py[16], pz[16], d[16];
    #pragma unroll
    for (int j = 0; j < 16; ++j) {
        int p = j * 256 + t;
        px[j] = pb[p * 3 + 0];
        py[j] = pb[p * 3 + 1];
        pz[j] = pb[p * 3 + 2];
    }
    int far;
    if (it0 == 0) {
        #pragma unroll
        for (int j = 0; j < 16; ++j) d[j] = 1e10f;
        far = 0;
    } else {
        #pragma unroll
        for (int j = 0; j < 16; ++j) d[j] = dws[b * 4096 + j * 256 + t];
        far = farws[b];
    }
    for (int it = it0; it < it1; ++it) {
        const int par = it & 1;
        if (t == 0) { inds_i[it] = far; inds_f[it] = (float)far; }
        const float cx = pb[far * 3 + 0];
        const float cy = pb[far * 3 + 1];
        const float cz = pb[far * 3 + 2];
        d[0] = fminf(d[0], dist2e(px[0], py[0], pz[0], cx, cy, cz));
        unsigned long long best = packdi(d[0], t);
        #pragma unroll
        for (int j = 1; j < 16; ++j) {
            d[j] = fminf(d[j], dist2e(px[j], py[j], pz[j], cx, cy, cz));
            unsigned long long c = packdi(d[j], j * 256 + t);
            if (c > best) best = c;
        }
        const unsigned hi = (unsigned)(best >> 32);
        const unsigned lo = (unsigned)(best & 0xFFFFFFFFull);
        float m = __uint_as_float(hi);
        m = dpp_maxf<0x111>(m);
        m = dpp_maxf<0x112>(m);
        m = dpp_maxf<0x114>(m);
        m = dpp_maxf<0x118>(m);
        m = dpp_maxf<0x142>(m);
        m = dpp_maxf<0x143>(m);
        const unsigned mbits = (unsigned)__builtin_amdgcn_readlane(__float_as_int(m), 63);
        unsigned cand = (hi == mbits) ? lo : 0u;
        cand = dpp_maxu<0x111>(cand);
        cand = dpp_maxu<0x112>(cand);
        cand = dpp_maxu<0x114>(cand);
        cand = dpp_maxu<0x118>(cand);
        cand = dpp_maxu<0x142>(cand);
        cand = dpp_maxu<0x143>(cand);
        const unsigned wlo = (unsigned)__builtin_amdgcn_readlane((int)cand, 63);
        if (lane == 0)
            s_red[par][wid] = ((unsigned long long)mbits << 32) | (unsigned long long)wlo;
        __syncthreads();
        unsigned long long mm = s_red[par][0];
        if (s_red[par][1] > mm) mm = s_red[par][1];
        if (s_red[par][2] > mm) mm = s_red[par][2];
        if (s_red[par][3] > mm) mm = s_red[par][3];
        far = (int)(0xFFFFFFFFu - (unsigned)(mm & 0xFFFFFFFFull));
    }
    if (it1 < 256) {
        #pragma unroll
        for (int j = 0; j < 16; ++j) dws[b * 4096 + j * 256 + t] = d[j];
        if (t == 0) farws[b] = far;
    }
}

// ---------------- split-bf16 MFMA FFN GEMM (+ FPS carrier) -------------------
// R10 structure; epilogue stores reordered (j outer / fn inner) so consecutive
// store instructions fill consecutive 64B halves of each 128B line (write
// combining). Stats pass FP order unchanged -> bit-identical psum/psqr.
template <bool PRE_BN, bool STATS>
__global__ __launch_bounds__(256, 4)
void fgemm_k(const float* __restrict__ X,
             const unsigned short* __restrict__ Wh,
             const unsigned short* __restrict__ Wl,
             const float* __restrict__ bias,
             const float* __restrict__ scl, const float* __restrict__ sft,
             float* __restrict__ Y,
             float* __restrict__ psum, float* __restrict__ psqr,
             const float* __restrict__ xyz, int* __restrict__ sinds,
             float* __restrict__ inds_f, float* __restrict__ fpsd,
             int* __restrict__ fpsfar, int it0, int it1) {
    __shared__ __align__(16) unsigned short sBh[128 * 64];
    __shared__ __align__(16) unsigned short sBl[128 * 64];
    if (blockIdx.x < 16) {
        fps_seg(xyz, blockIdx.x, it0, it1, sinds + blockIdx.x * 256,
                inds_f + blockIdx.x * 256, fpsd, fpsfar, (char*)sBh);
        return;
    }
    int idx = blockIdx.x - 16;
    idx = (idx & 7) * 128 + (idx >> 3);
    const int b = idx >> 6, rem = idx & 63;
    const int nt = rem >> 1;
    const int n0 = nt * 128, o0 = (rem & 1) * 128;
    const int t = threadIdx.x;
    const int w = t >> 6, lane = t & 63;
    const int wm = (w >> 1) * 64, wn = (w & 1) * 64;
    const int lr = lane & 15, lk = lane >> 4;
    char* cBh = (char*)sBh;
    char* cBl = (char*)sBl;

    v4f acc[4][4];
    v4f zz = {0.f, 0.f, 0.f, 0.f};
    #pragma unroll
    for (int i = 0; i < 4; ++i)
        #pragma unroll
        for (int j = 0; j < 4; ++j) acc[i][j] = zz;

    const size_t aoff = (size_t)(o0 + wm + lr) * 256 + lk * 8;
    const unsigned short* pah = Wh + aoff;
    const unsigned short* pal = Wl + aoff;

    const int cblk = t >> 5, nq = t & 31;
    const float* xb = X + ((size_t)b * 256 + cblk * 8) * 4096 + n0 + nq * 4;

    v4f cur[8];
    #pragma unroll
    for (int i = 0; i < 8; ++i)
        cur[i] = *(const v4f*)(xb + (size_t)i * 4096);
    if (PRE_BN) bn8(cur, scl, sft, cblk * 8);

    #pragma unroll
    for (int ks = 0; ks < 4; ++ks) {
        const int k0 = ks * 64;
        // B1: LDS-overwrite guard only; no vmem/lgkm drain attached.
        barrier_plain();
        #pragma unroll
        for (int j = 0; j < 4; ++j) {
            const int n = nq * 4 + j;
            uint2 p0 = split2(cur[0][j], cur[1][j]);
            uint2 p1 = split2(cur[2][j], cur[3][j]);
            uint2 p2 = split2(cur[4][j], cur[5][j]);
            uint2 p3 = split2(cur[6][j], cur[7][j]);
            uint4 hh, ll;
            hh.x = p0.x; hh.y = p1.x; hh.z = p2.x; hh.w = p3.x;
            ll.x = p0.y; ll.y = p1.y; ll.z = p2.y; ll.w = p3.y;
            const int ad = n * 128 + ((cblk * 16) ^ ((n & 7) << 4));
            *(uint4*)(cBh + ad) = hh;
            *(uint4*)(cBl + ad) = ll;
        }
        // B2: my ds_writes visible to all waves; vmem loads left in flight.
        barrier_lgkm();
        // prefetch next tile: stays in flight through the MFMA phase AND the
        // next iteration's barriers, until split2's first use of cur.
        if (ks < 3) {
            #pragma unroll
            for (int i = 0; i < 8; ++i)
                cur[i] = *(const v4f*)(xb + (size_t)(k0 + 64 + i) * 4096);
            if (PRE_BN) bn8(cur, scl, sft, k0 + 64 + cblk * 8);
        }
        #pragma unroll
        for (int kb = 0; kb < 2; ++kb) {
            const int koff = kb * 64 + lk * 16;
            const int ka = k0 + kb * 32;
            v8s ahf[4], alf[4], bhf[4], blf[4];
            #pragma unroll
            for (int f = 0; f < 4; ++f) {
                ahf[f] = *(const v8s*)(pah + (size_t)f * 4096 + ka);
                alf[f] = *(const v8s*)(pal + (size_t)f * 4096 + ka);
                const int rn = wn + f * 16 + lr;
                const int bm = rn * 128 + (koff ^ ((rn & 7) << 4));
                bhf[f] = *(const v8s*)(cBh + bm);
                blf[f] = *(const v8s*)(cBl + bm);
            }
            #pragma unroll
            for (int fm = 0; fm < 4; ++fm)
                #pragma unroll
                for (int fn = 0; fn < 4; ++fn) {
                    acc[fm][fn] = __builtin_amdgcn_mfma_f32_16x16x32_bf16(
                        ahf[fm], bhf[fn], acc[fm][fn], 0, 0, 0);
                    acc[fm][fn] = __builtin_amdgcn_mfma_f32_16x16x32_bf16(
                        ahf[fm], blf[fn], acc[fm][fn], 0, 0, 0);
                    acc[fm][fn] = __builtin_amdgcn_mfma_f32_16x16x32_bf16(
                        alf[fm], bhf[fn], acc[fm][fn], 0, 0, 0);
                }
        }
    }

    float* Yb = Y + (size_t)b * 256 * 4096;
    const int gnt = b * 32 + nt;
    #pragma unroll
    for (int fm = 0; fm < 4; ++fm) {
        const int obase = o0 + wm + fm * 16 + lk * 4;
        float bv[4];
        #pragma unroll
        for (int j = 0; j < 4; ++j) bv[j] = bias[obase + j];
        // stats pass: FP order identical to previous rounds (no stores here)
        float ssr[4] = {0.f, 0.f, 0.f, 0.f}, qqr[4] = {0.f, 0.f, 0.f, 0.f};
        if (STATS) {
            #pragma unroll
            for (int fn = 0; fn < 4; ++fn) {
                #pragma unroll
                for (int j = 0; j < 4; ++j) {
                    const float yv = acc[fm][fn][j] + bv[j];
                    ssr[j] += yv; qqr[j] += yv * yv;
                }
            }
        }
        // store pass: j outer / fn inner -> per 16-lane row group, the 4 fn
        // stores are consecutive 64B segments (256B contiguous) of one row.
        #pragma unroll
        for (int j = 0; j < 4; ++j) {
            float* yrow = Yb + (size_t)(obase + j) * 4096 + n0 + wn + lr;
            const float bvj = bv[j];
            #pragma unroll
            for (int fn = 0; fn < 4; ++fn)
                yrow[fn * 16] = acc[fm][fn][j] + bvj;
        }
        if (STATS) {
            #pragma unroll
            for (int j = 0; j < 4; ++j) {
                #pragma unroll
                for (int off = 1; off < 16; off <<= 1) {
                    ssr[j] += __shfl_xor(ssr[j], off, 64);
                    qqr[j] += __shfl_xor(qqr[j], off, 64);
                }
            }
            if (lr == 0) {
                const int col = gnt * 2 + (w & 1);
                #pragma unroll
                for (int j = 0; j < 4; ++j) {
                    psum[(size_t)(obase + j) * 1024 + col] = ssr[j];
                    psqr[(size_t)(obase + j) * 1024 + col] = qqr[j];
                }
            }
        }
    }
}

// ---------------- FFN weight split preconvert (hi/lo bf16 planes) -------------
__global__ __launch_bounds__(256)
void prepw_k(const float* __restrict__ W1, const float* __restrict__ W2,
             const float* __restrict__ W3, unsigned short* __restrict__ h1,
             unsigned short* __restrict__ l1, unsigned short* __restrict__ h2,
             unsigned short* __restrict__ l2, unsigned short* __restrict__ h3,
             unsigned short* __restrict__ l3) {
    const int o = blockIdx.x & 255, which = blockIdx.x >> 8, t = threadIdx.x;
    float v;
    unsigned short* ph;
    unsigned short* pl;
    if (which == 0) { v = W1[(size_t)o * 256 + t]; ph = h1; pl = l1; }
    else if (which == 1) { v = W2[(size_t)o * 256 + t]; ph = h2; pl = l2; }
    else { v = W3[(size_t)(o + 3) * 256 + t]; ph = h3; pl = l3; }  // rows 3..258
    unsigned short hu = f2bf(v);
    float rv = v - __uint_as_float((unsigned)hu << 16);
    ph[o * 256 + t] = hu;
    pl[o * 256 + t] = f2bf(rv);
}

// ---------------- BN finalize: npart partials -> scale/shift ------------------
__global__ __launch_bounds__(64)
void fin_k(const float* __restrict__ psum, const float* __restrict__ psqr,
           const float* __restrict__ g, const float* __restrict__ be,
           float* __restrict__ scl, float* __restrict__ sft, int npart) {
    const int c = blockIdx.x, t = threadIdx.x;
    const float4* ps = (const float4*)(psum + (size_t)c * 1024);
    const float4* pq = (const float4*)(psqr + (size_t)c * 1024);
    float s = 0.f, q = 0.f;
    for (int r = t; r < (npart >> 2); r += 64) {
        float4 a = ps[r]; s += a.x + a.y + a.z + a.w;
        float4 b2 = pq[r]; q += b2.x + b2.y + b2.z + b2.w;
    }
    #pragma unroll
    for (int sh = 32; sh; sh >>= 1) {
        s += __shfl_down(s, (unsigned)sh, 64);
        q += __shfl_down(q, (unsigned)sh, 64);
    }
    if (t == 0) {
        float mean = s * (1.f / 65536.f);
        float var = q * (1.f / 65536.f) - mean * mean;
        float sc = g[c] / sqrtf(var + 1e-5f);
        scl[c] = sc;
        sft[c] = be[c] - mean * sc;
    }
}

// ---------------- weight preconvert to bf16 (permuted mW1) --------------------
__global__ __launch_bounds__(256)
void prep_k(const float* __restrict__ mW1, const float* __restrict__ mW2,
            const float* __restrict__ mW3, unsigned short* __restrict__ W1p,
            unsigned short* __restrict__ W2p, unsigned short* __restrict__ W3p) {
    const int o = blockIdx.x & 255, which = blockIdx.x >> 8, t = threadIdx.x;
    if (which == 0) {
        W1p[o * 320 + t] = f2bf(mW1[o * 259 + 3 + t]);
        if (t < 64) {
            float v = (t < 3) ? mW1[o * 259 + t] : 0.f;
            W1p[o * 320 + 256 + t] = f2bf(v);
        }
    } else if (which == 1) {
        W2p[o * 256 + t] = f2bf(mW2[o * 256 + t]);
    } else {
        W3p[o * 256 + t] = f2bf(mW3[o * 256 + t]);
    }
}

// ---------------- vote_xyz (exact f32 coord dots) + normalized featT (bf16) ---
// Vectorized loads: each thread covers 4 n x 1 c, 8 channel passes.
// carries FPS segment 4 (blocks 0..15)
__global__ __launch_bounds__(256)
void votefeat_k(const float* __restrict__ OUT, const float* __restrict__ Y2,
                const float* __restrict__ xyz, const float* __restrict__ feats,
                const float* __restrict__ scl2, const float* __restrict__ sft2,
                const float* __restrict__ W3, const float* __restrict__ b3,
                float* __restrict__ vote_out, float* __restrict__ xyz_out,
                unsigned short* __restrict__ featT,
                int* __restrict__ sinds, float* __restrict__ inds_f,
                float* __restrict__ fpsd, int* __restrict__ fpsfar,
                int it0, int it1) {
    __shared__ float tile[32 * 257];
    __shared__ float ssb[32][33];
    __shared__ float rn[32];
    __shared__ float sW3[768];
    __shared__ float dred[3][32][33];
    if (blockIdx.x < 16) {
        fps_seg(xyz, blockIdx.x, it0, it1, sinds + blockIdx.x * 256,
                inds_f + blockIdx.x * 256, fpsd, fpsfar, (char*)tile);
        return;
    }
    const int blk = blockIdx.x - 16;
    const int b = blk >> 7, n0 = (blk & 127) * 32;
    const int t = threadIdx.x;
    const int nl4 = (t & 7) * 4, sl = t >> 3;  // 4-n block, channel slice 0..31
    const float* Fb = feats + (size_t)b * 256 * NPT;
    const float* Ob = OUT + (size_t)b * 256 * NPT;
    const float* Yb = Y2 + (size_t)b * 256 * NPT;
    #pragma unroll
    for (int r = 0; r < 3; ++r) sW3[r * 256 + t] = W3[r * 256 + t];
    __syncthreads();
    float ss[4] = {0.f, 0.f, 0.f, 0.f};
    float dd[3][4];
    #pragma unroll
    for (int r = 0; r < 3; ++r)
        #pragma unroll
        for (int j = 0; j < 4; ++j) dd[r][j] = 0.f;
    #pragma unroll
    for (int ci = 0; ci < 8; ++ci) {
        const int c = ci * 32 + sl;
        const size_t coff = (size_t)c * NPT + n0 + nl4;
        const v4f f4 = *(const v4f*)(Fb + coff);
        const v4f o4 = *(const v4f*)(Ob + coff);
        const v4f y4 = *(const v4f*)(Yb + coff);
        const float s2 = scl2[c], sh2 = sft2[c];
        const float w0 = sW3[c], w1 = sW3[256 + c], w2 = sW3[512 + c];
        #pragma unroll
        for (int j = 0; j < 4; ++j) {
            const float v = f4[j] + o4[j];
            tile[(nl4 + j) * 257 + c] = v;
            ss[j] = fmaf(v, v, ss[j]);
            const float h = fmaxf(fmaf(y4[j], s2, sh2), 0.f);
            dd[0][j] = fmaf(h, w0, dd[0][j]);
            dd[1][j] = fmaf(h, w1, dd[1][j]);
            dd[2][j] = fmaf(h, w2, dd[2][j]);
        }
    }
    #pragma unroll
    for (int j = 0; j < 4; ++j) ssb[nl4 + j][sl] = ss[j];
    #pragma unroll
    for (int r = 0; r < 3; ++r)
        #pragma unroll
        for (int j = 0; j < 4; ++j) dred[r][nl4 + j][sl] = dd[r][j];
    __syncthreads();
    if (t < 32) {
        float s = 0.f;
        #pragma unroll
        for (int k = 0; k < 32; ++k) s += ssb[t][k];
        rn[t] = 1.0f / sqrtf(s);
    }
    __syncthreads();
    // featT: vectorized 8B stores (4 channels per thread per pass)
    #pragma unroll
    for (int pp = 0; pp < 8; ++pp) {
        const int p = pp * 4 + (t >> 6);
        const int ch = (t & 63) * 4;
        const float rv = rn[p];
        const float v0 = tile[p * 257 + ch + 0] * rv;
        const float v1 = tile[p * 257 + ch + 1] * rv;
        const float v2 = tile[p * 257 + ch + 2] * rv;
        const float v3 = tile[p * 257 + ch + 3] * rv;
        *(uint2*)&featT[((size_t)b * NPT + n0 + p) * 256 + ch] =
            make_uint2(pk2(v0, v1), pk2(v2, v3));
    }
    if (t < 96) {
        const int r = t >> 5, p = t & 31;
        float d = b3[r];
        #pragma unroll
        for (int k = 0; k < 32; ++k) d += dred[r][p][k];
        float sig = 1.f / (1.f + expf(-d));
        sig = fminf(fmaxf(sig, 0.1f), 0.9f);
        const size_t gi = ((size_t)b * NPT + n0 + p) * 3 + r;
        const float e = xyz[gi];
        vote_out[gi] = e + sig - 0.5f;
        xyz_out[gi] = e;
    }
}

// ---------------- ball query: one wave per (b,q) ------------------------------
__global__ __launch_bounds__(64)
void bq_k(const float* __restrict__ vote, const int* __restrict__ sinds,
          float* __restrict__ qxyz_out, int* __restrict__ idx_out) {
    const int bq = blockIdx.x;
    const int b = bq >> 8;
    const int lane = threadIdx.x;
    __shared__ int s_idx[16];
    const int si = sinds[bq];
    const float* vb = vote + (size_t)b * NPT * 3;
    const float qx = vb[si * 3 + 0], qy = vb[si * 3 + 1], qz = vb[si * 3 + 2];
    if (lane < 3) qxyz_out[bq * 3 + lane] = vb[si * 3 + lane];
    int cnt = 0;
    for (int cb = 0; cb < 64 && cnt < 16; ++cb) {
        int n = cb * 64 + lane;
        float x = vb[n * 3], y = vb[n * 3 + 1], z = vb[n * 3 + 2];
        float d2 = dist2e(x, y, z, qx, qy, qz);
        unsigned long long m = __ballot(d2 < 0.09f);
        while (m && cnt < 16) {
            int bit = __builtin_ctzll(m);
            s_idx[cnt] = cb * 64 + bit;
            ++cnt;
            m &= m - 1;
        }
    }
    __syncthreads();
    if (lane < 16) {
        int v = (lane < cnt) ? s_idx[lane] : (cnt > 0 ? s_idx[0] : 0);
        idx_out[bq * 16 + lane] = v;
    }
}

// ---------------- grouping: build G^T bf16 [65536][320] (permuted cols) -------
__global__ __launch_bounds__(256)
void group_k(const unsigned short* __restrict__ featT, const float* __restrict__ vote,
             const float* __restrict__ qxyz, const int* __restrict__ idxs,
             unsigned short* __restrict__ Gt) {
    const int bq = blockIdx.x;
    const int b = bq >> 8, q = bq & 255;
    const int t = threadIdx.x;
    __shared__ int s_i[16];
    __shared__ float s_q[3];
    if (t < 16) s_i[t] = idxs[bq * 16 + t];
    if (t < 3) s_q[t] = qxyz[bq * 3 + t];
    __syncthreads();
    const int s = t >> 4, part = t & 15;
    const int i = s_i[s];
    const size_t nrow = (size_t)b * 4096 + q * 16 + s;
    const uint4* src = (const uint4*)(featT + ((size_t)b * NPT + i) * 256 + part * 16);
    uint4* dst = (uint4*)(Gt + nrow * 320 + part * 16);
    dst[0] = src[0];
    dst[1] = src[1];
    for (int c = 259 + part; c < 320; c += 16) Gt[nrow * 320 + c] = 0;
    if (part < 3) {
        float v = (vote[((size_t)b * NPT + i) * 3 + part] - s_q[part]) * (1.f / 0.3f);
        Gt[nrow * 320 + 256 + part] = f2bf(v);
    }
}

// ---------------- bf16 MFMA GEMM: Y^T[n][o] = sum_k W[o][k] X^T[n][k] ---------
// A (weights) read direct from global (L2-hot, shared by all blocks);
// only B staged in LDS (16 KB) -> 4 blocks/CU. Raw barriers with fences.
// Epilogue stores reordered (fn outer / fm inner) for 128B write combining.
__device__ __forceinline__ unsigned bnpair(unsigned u, float sl, float sh,
                                           float fl, float fh) {
    float lo = __uint_as_float(u << 16);
    float hi = __uint_as_float(u & 0xFFFF0000u);
    lo = fmaxf(fmaf(lo, sl, fl), 0.f);
    hi = fmaxf(fmaf(hi, sh, fh), 0.f);
    unsigned r;
    asm("v_cvt_pk_bf16_f32 %0, %1, %2" : "=v"(r) : "v"(lo), "v"(hi));
    return r;
}

template <int KPAD, bool BNSTAGE, bool EPIMAX>
__global__ __launch_bounds__(256, 4)
void mgemm_k(const unsigned short* __restrict__ Wb,
             const unsigned short* __restrict__ Xt,
             const float* __restrict__ bias,
             const float* __restrict__ scl, const float* __restrict__ sft,
             unsigned short* __restrict__ Yt, float* __restrict__ rmax,
             float* __restrict__ psum, float* __restrict__ psqr) {
    __shared__ __align__(16) unsigned short sB[128 * 64];
    char* cB = (char*)sB;
    const int t = threadIdx.x;
    const int n0 = blockIdx.x * 128, o0 = blockIdx.y * 128;
    const int w = t >> 6, lane = t & 63;
    const int wm = (w >> 1) * 64, wn = (w & 1) * 64;
    const int lr = lane & 15, lk = lane >> 4;

    v4f acc[4][4];
    v4f zz = {0.f, 0.f, 0.f, 0.f};
    #pragma unroll
    for (int i = 0; i < 4; ++i)
        #pragma unroll
        for (int j = 0; j < 4; ++j) acc[i][j] = zz;

    // A direct-from-global base (per-thread)
    const unsigned short* pa = Wb + (size_t)(o0 + wm + lr) * KPAD + lk * 8;

    const int ra = t >> 1, kc = (t & 1) * 32;
    const unsigned short* bsrc = Xt + (size_t)(n0 + ra) * KPAD + kc;
    constexpr int nk = KPAD / 64;

    // prologue: B tile 0 -> regs (+BN)
    uint4 bv[4];
    #pragma unroll
    for (int i = 0; i < 4; ++i) bv[i] = *(const uint4*)(bsrc + 8 * i);
    if constexpr (BNSTAGE) {
        #pragma unroll
        for (int i = 0; i < 4; ++i) {
            const int kk = kc + 8 * i;
            float4 s0 = *(const float4*)(scl + kk);
            float4 s1 = *(const float4*)(scl + kk + 4);
            float4 f0 = *(const float4*)(sft + kk);
            float4 f1 = *(const float4*)(sft + kk + 4);
            bv[i].x = bnpair(bv[i].x, s0.x, s0.y, f0.x, f0.y);
            bv[i].y = bnpair(bv[i].y, s0.z, s0.w, f0.z, f0.w);
            bv[i].z = bnpair(bv[i].z, s1.x, s1.y, f1.x, f1.y);
            bv[i].w = bnpair(bv[i].w, s1.z, s1.w, f1.z, f1.w);
        }
    }

    #pragma unroll
    for (int ks = 0; ks < nk; ++ks) {
        // B1: LDS-overwrite guard only.
        barrier_plain();
        #pragma unroll
        for (int i = 0; i < 4; ++i) {
            const int kb2 = (kc + 8 * i) * 2;
            *(uint4*)(cB + ra * 128 + (kb2 ^ ((ra & 7) << 4))) = bv[i];
        }
        // B2: ds_write visibility; vmem loads left in flight.
        barrier_lgkm();
        // prefetch next B K-tile (in flight until next iteration's ds_write)
        if (ks + 1 < nk) {
            const int k1 = (ks + 1) * 64;
            #pragma unroll
            for (int i = 0; i < 4; ++i) bv[i] = *(const uint4*)(bsrc + k1 + 8 * i);
            if constexpr (BNSTAGE) {
                #pragma unroll
                for (int i = 0; i < 4; ++i) {
                    const int kk = k1 + kc + 8 * i;
                    float4 s0 = *(const float4*)(scl + kk);
                    float4 s1 = *(const float4*)(scl + kk + 4);
                    float4 f0 = *(const float4*)(sft + kk);
                    float4 f1 = *(const float4*)(sft + kk + 4);
                    bv[i].x = bnpair(bv[i].x, s0.x, s0.y, f0.x, f0.y);
                    bv[i].y = bnpair(bv[i].y, s0.z, s0.w, f0.z, f0.w);
                    bv[i].z = bnpair(bv[i].z, s1.x, s1.y, f1.x, f1.y);
                    bv[i].w = bnpair(bv[i].w, s1.z, s1.w, f1.z, f1.w);
                }
            }
        }
        #pragma unroll
        for (int kb = 0; kb < 2; ++kb) {
            const int koff = (kb * 32 + lk * 8) * 2;
            const int ka = ks * 64 + kb * 32;
            v8s af[4], bf[4];
            #pragma unroll
            for (int f = 0; f < 4; ++f) {
                af[f] = *(const v8s*)(pa + (size_t)(f * 16) * KPAD + ka);
                const int rn = wn + f * 16 + lr;
                bf[f] = *(const v8s*)(cB + rn * 128 + (koff ^ ((rn & 7) << 4)));
            }
            #pragma unroll
            for (int fm = 0; fm < 4; ++fm)
                #pragma unroll
                for (int fn = 0; fn < 4; ++fn)
                    acc[fm][fn] = __builtin_amdgcn_mfma_f32_16x16x32_bf16(
                        af[fm], bf[fn], acc[fm][fn], 0, 0, 0);
        }
    }

    // epilogue: stats (+q-max) pass, then coalesced-order store pass
    const int bx = blockIdx.x;
    #pragma unroll
    for (int fm = 0; fm < 4; ++fm) {
        const int obase = o0 + wm + fm * 16 + lk * 4;
        const float4 bv4 = *(const float4*)(bias + obase);
        float s0 = 0.f, s1 = 0.f, s2 = 0.f, s3 = 0.f;
        float q0 = 0.f, q1 = 0.f, q2 = 0.f, q3 = 0.f;
        #pragma unroll
        for (int fn = 0; fn < 4; ++fn) {
            float y0 = acc[fm][fn][0] + bv4.x;
            float y1 = acc[fm][fn][1] + bv4.y;
            float y2 = acc[fm][fn][2] + bv4.z;
            float y3 = acc[fm][fn][3] + bv4.w;
            s0 += y0; s1 += y1; s2 += y2; s3 += y3;
            q0 += y0 * y0; q1 += y1 * y1; q2 += y2 * y2; q3 += y3 * y3;
            if constexpr (EPIMAX) {
                float m0 = y0, m1 = y1, m2 = y2, m3 = y3;
                #pragma unroll
                for (int off = 1; off < 16; off <<= 1) {
                    m0 = fmaxf(m0, __shfl_xor(m0, off, 64));
                    m1 = fmaxf(m1, __shfl_xor(m1, off, 64));
                    m2 = fmaxf(m2, __shfl_xor(m2, off, 64));
                    m3 = fmaxf(m3, __shfl_xor(m3, off, 64));
                }
                if (lr == 0) {
                    const int gq = (n0 + wn + fn * 16) >> 4;
                    const int bb = gq >> 8, qq = gq & 255;
                    float* rp = rmax + ((size_t)bb * 256 + obase) * 256 + qq;
                    rp[0] = m0; rp[256] = m1; rp[512] = m2; rp[768] = m3;
                }
            }
        }
        #pragma unroll
        for (int off = 1; off < 16; off <<= 1) {
            s0 += __shfl_xor(s0, off, 64); q0 += __shfl_xor(q0, off, 64);
            s1 += __shfl_xor(s1, off, 64); q1 += __shfl_xor(q1, off, 64);
            s2 += __shfl_xor(s2, off, 64); q2 += __shfl_xor(q2, off, 64);
            s3 += __shfl_xor(s3, off, 64); q3 += __shfl_xor(q3, off, 64);
        }
        if (lr == 0) {
            const int col = bx * 2 + (w & 1);
            psum[(size_t)(obase + 0) * 1024 + col] = s0;
            psum[(size_t)(obase + 1) * 1024 + col] = s1;
            psum[(size_t)(obase + 2) * 1024 + col] = s2;
            psum[(size_t)(obase + 3) * 1024 + col] = s3;
            psqr[(size_t)(obase + 0) * 1024 + col] = q0;
            psqr[(size_t)(obase + 1) * 1024 + col] = q1;
            psqr[(size_t)(obase + 2) * 1024 + col] = q2;
            psqr[(size_t)(obase + 3) * 1024 + col] = q3;
        }
    }
    if constexpr (!EPIMAX) {
        // store pass: fn outer / fm inner -> per n-row, the 4 fm stores fill
        // 4 consecutive 32B quarters of a 128B line across the lk lanes.
        #pragma unroll
        for (int fn = 0; fn < 4; ++fn) {
            const int gn = n0 + wn + fn * 16 + lr;
            unsigned short* yrow = Yt + (size_t)gn * 256 + o0 + wm + lk * 4;
            #pragma unroll
            for (int fm = 0; fm < 4; ++fm) {
                const float4 bv4 = *(const float4*)(bias + o0 + wm + fm * 16 + lk * 4);
                const float y0 = acc[fm][fn][0] + bv4.x;
                const float y1 = acc[fm][fn][1] + bv4.y;
                const float y2 = acc[fm][fn][2] + bv4.z;
                const float y3 = acc[fm][fn][3] + bv4.w;
                *(uint2*)(yrow + fm * 16) = make_uint2(pk2(y0, y1), pk2(y2, y3));
            }
        }
    }
}

// ---------------- final: qf = relu(sc*rawmax + sh) ----------------------------
__global__ __launch_bounds__(256)
void qf_k(const float* __restrict__ rmax, const float* __restrict__ scl,
          const float* __restrict__ sft, float* __restrict__ out) {
    const int g = blockIdx.x * 256 + threadIdx.x;
    const int c = (g >> 8) & 255;
    out[g] = fmaxf(fmaf(rmax[g], scl[c], sft[c]), 0.f);
}

extern "C" void kernel_launch(void* const* d_in, const int* in_sizes, int n_in,
                              void* d_out, int out_size, void* d_ws, size_t ws_size,
                              hipStream_t stream) {
    const float* xyz   = (const float*)d_in[0];
    const float* feats = (const float*)d_in[1];
    const float* W1 = (const float*)d_in[2];
    const float* b1 = (const float*)d_in[3];
    const float* g1 = (const float*)d_in[4];
    const float* be1 = (const float*)d_in[5];
    const float* W2 = (const float*)d_in[6];
    const float* b2 = (const float*)d_in[7];
    const float* g2 = (const float*)d_in[8];
    const float* be2 = (const float*)d_in[9];
    const float* W3 = (const float*)d_in[10];
    const float* b3 = (const float*)d_in[11];
    const float* mW1 = (const float*)d_in[12];
    const float* mb1 = (const float*)d_in[13];
    const float* mg1 = (const float*)d_in[14];
    const float* mbe1 = (const float*)d_in[15];
    const float* mW2 = (const float*)d_in[16];
    const float* mb2 = (const float*)d_in[17];
    const float* mg2 = (const float*)d_in[18];
    const float* mbe2 = (const float*)d_in[19];
    const float* mW3 = (const float*)d_in[20];
    const float* mb3 = (const float*)d_in[21];
    const float* mg3 = (const float*)d_in[22];
    const float* mbe3 = (const float*)d_in[23];

    float* out_vote = (float*)d_out;
    float* out_xyz = out_vote + 196608;
    float* out_inds = out_xyz + 196608;
    float* out_q = out_inds + 4096;
    float* out_qf = out_q + 12288;

    // ws layout (floats) — unchanged footprint
    float* ws = (float*)d_ws;
    float* A      = ws;                      // 16973824 f : y1 -> OUT -> Gt(bf16)
    float* Bb     = A + 16973824;            // 16777216 f : y2 -> Y1t(bf16)
    float* Ft     = Bb + 16777216;           // 8388608 f  : featT(bf16) -> Y2t(bf16)
    float* rawmax = Ft + 8388608;            // 1048576 f (front reused for W planes)
    float* psum   = rawmax + 1048576;        // 262144
    float* psqr   = psum + 262144;           // 262144
    float* st     = psqr + 262144;           // 2560
    float* fpsd   = st + 2560;               // 65536
    float* wbase  = fpsd + 65536;
    unsigned short* Wb1 = (unsigned short*)wbase;           // 81920 h
    unsigned short* Wb2 = Wb1 + 81920;                      // 65536 h
    unsigned short* Wb3 = Wb2 + 65536;                      // 65536 h
    int* sinds  = (int*)(Wb3 + 65536);
    int* bidx   = sinds + 4096;
    int* fpsfar = bidx + 65536;

    unsigned short* Gt  = (unsigned short*)A;
    unsigned short* Y1t = (unsigned short*)Bb;
    unsigned short* featT = (unsigned short*)Ft;
    unsigned short* Y2t = (unsigned short*)Ft;

    // FFN split-bf16 weight planes: carved from rawmax region (dead until mgemm3)
    unsigned short* Wf1h = (unsigned short*)rawmax;
    unsigned short* Wf1l = Wf1h + 65536;
    unsigned short* Wf2h = Wf1l + 65536;
    unsigned short* Wf2l = Wf2h + 65536;
    unsigned short* Wf3h = Wf2l + 65536;
    unsigned short* Wf3l = Wf3h + 65536;     // total 393216 h = 196608 f < 1048576

    prep_k<<<768, 256, 0, stream>>>(mW1, mW2, mW3, Wb1, Wb2, Wb3);
    prepw_k<<<768, 256, 0, stream>>>(W1, W2, W3, Wf1h, Wf1l, Wf2h, Wf2l, Wf3h, Wf3l);

    // FFN as split-bf16 MFMA GEMMs; FPS split into 4x64-iter hidden segments
    fgemm_k<false, true><<<1040, 256, 0, stream>>>(
        feats, Wf1h, Wf1l, b1, nullptr, nullptr, A, psum, psqr,
        xyz, sinds, out_inds, fpsd, fpsfar, 0, 64);
    fin_k<<<256, 64, 0, stream>>>(psum, psqr, g1, be1, st + 0, st + 256, 1024);
    fgemm_k<true, true><<<1040, 256, 0, stream>>>(
        A, Wf2h, Wf2l, b2, st + 0, st + 256, Bb, psum, psqr,
        xyz, sinds, out_inds, fpsd, fpsfar, 64, 128);
    fin_k<<<256, 64, 0, stream>>>(psum, psqr, g2, be2, st + 512, st + 768, 1024);
    // GEMM3: only the 256 feature-delta rows (W3 rows 3..258); coord rows 0..2
    // are computed exactly in f32 inside votefeat_k from y2 (Bb).
    fgemm_k<true, false><<<1040, 256, 0, stream>>>(
        Bb, Wf3h, Wf3l, b3 + 3, st + 512, st + 768, A, nullptr, nullptr,
        xyz, sinds, out_inds, fpsd, fpsfar, 128, 192);

    votefeat_k<<<2064, 256, 0, stream>>>(A, Bb, xyz, feats, st + 512, st + 768,
                                         W3, b3, out_vote, out_xyz, featT,
                                         sinds, out_inds, fpsd, fpsfar, 192, 256);
    bq_k<<<4096, 64, 0, stream>>>(out_vote, sinds, out_q, bidx);
    group_k<<<4096, 256, 0, stream>>>(featT, out_vote, out_q, bidx, Gt);

    // SA MLP: bf16 MFMA GEMMs (A-direct, 4 blocks/CU, raw barriers + fences)
    mgemm_k<320, false, false><<<dim3(512, 2), 256, 0, stream>>>(
        Wb1, Gt, mb1, nullptr, nullptr, Y1t, nullptr, psum, psqr);
    fin_k<<<256, 64, 0, stream>>>(psum, psqr, mg1, mbe1, st + 1024, st + 1280, 1024);
    mgemm_k<256, true, false><<<dim3(512, 2), 256, 0, stream>>>(
        Wb2, Y1t, mb2, st + 1024, st + 1280, Y2t, nullptr, psum, psqr);
    fin_k<<<256, 64, 0, stream>>>(psum, psqr, mg2, mbe2, st + 1536, st + 1792, 1024);
    mgemm_k<256, true, true><<<dim3(512, 2), 256, 0, stream>>>(
        Wb3, Y2t, mb3, st + 1536, st + 1792, nullptr, rawmax, psum, psqr);
    fin_k<<<256, 64, 0, stream>>>(psum, psqr, mg3, mbe3, st + 2048, st + 2304, 1024);
    qf_k<<<4096, 256, 0, stream>>>(rawmax, st + 2048, st + 2304, out_qf);
}

// Round 12
// 522.967 us; speedup vs baseline: 1.0584x; 1.0584x over previous
//
#include <hip/hip_runtime.h>
#include <math.h>

#define NPT 4096
#define NB 16

typedef short v8s __attribute__((ext_vector_type(8)));
typedef float v4f __attribute__((ext_vector_type(4)));

__device__ __forceinline__ float dist2e(float x, float y, float z,
                                        float cx, float cy, float cz) {
    float dx = __fsub_rn(x, cx), dy = __fsub_rn(y, cy), dz = __fsub_rn(z, cz);
    return __fadd_rn(__fadd_rn(__fmul_rn(dx, dx), __fmul_rn(dy, dy)), __fmul_rn(dz, dz));
}

__device__ __forceinline__ unsigned long long packdi(float v, int n) {
    return ((unsigned long long)__float_as_uint(v) << 32) |
           (unsigned long long)(0xFFFFFFFFu - (unsigned)n);
}

__device__ __forceinline__ unsigned short f2bf(float f) {
    unsigned u = __float_as_uint(f);
    u = u + 0x7FFFu + ((u >> 16) & 1u);
    return (unsigned short)(u >> 16);
}

// pack two f32 -> two bf16 (RNE), elem0 = a in low half
__device__ __forceinline__ unsigned pk2(float a, float b) {
    unsigned r;
    asm("v_cvt_pk_bf16_f32 %0, %1, %2" : "=v"(r) : "v"(a), "v"(b));
    return r;
}

// split (a,b) into bf16 hi pair + bf16 lo (residual) pair
__device__ __forceinline__ uint2 split2(float a, float b) {
    unsigned h = pk2(a, b);
    float ra = __uint_as_float(h << 16);
    float rb = __uint_as_float(h & 0xFFFF0000u);
    unsigned l = pk2(a - ra, b - rb);
    return make_uint2(h, l);
}

// BN+relu on 8 channels x 4 n held in regs
__device__ __forceinline__ void bn8(v4f* xv, const float* __restrict__ scl,
                                    const float* __restrict__ sft, int base) {
    const v4f s0 = *(const v4f*)(scl + base);
    const v4f s1 = *(const v4f*)(scl + base + 4);
    const v4f f0 = *(const v4f*)(sft + base);
    const v4f f1 = *(const v4f*)(sft + base + 4);
    #pragma unroll
    for (int i = 0; i < 8; ++i) {
        const float si = (i < 4) ? s0[i] : s1[i - 4];
        const float fi = (i < 4) ? f0[i] : f1[i - 4];
        #pragma unroll
        for (int j = 0; j < 4; ++j)
            xv[i][j] = fmaxf(fmaf(xv[i][j], si, fi), 0.f);
    }
}

// DPP wave64 max helpers (VALU-only reduce; result valid in lane 63)
template <int CTRL>
__device__ __forceinline__ float dpp_maxf(float v) {
    int o = __builtin_amdgcn_update_dpp(__float_as_int(v), __float_as_int(v),
                                        CTRL, 0xF, 0xF, false);
    return fmaxf(v, __int_as_float(o));
}
template <int CTRL>
__device__ __forceinline__ unsigned dpp_maxu(unsigned v) {
    unsigned o = (unsigned)__builtin_amdgcn_update_dpp((int)v, (int)v,
                                                       CTRL, 0xF, 0xF, false);
    return v > o ? v : o;
}

// ---------------- FPS segment: 256 threads, 16 register points per thread -----
__device__ void fps_seg(const float* __restrict__ xyz, int b, int it0, int it1,
                        int* __restrict__ inds_i, float* __restrict__ inds_f,
                        float* __restrict__ dws, int* __restrict__ farws,
                        char* scr) {
    unsigned long long (*s_red)[4] = (unsigned long long (*)[4])scr;
    const int t = threadIdx.x;
    const int lane = t & 63, wid = t >> 6;
    const float* pb = xyz + (size_t)b * NPT * 3;
    float px[16], py[16], pz[16], d[16];
    #pragma unroll
    for (int j = 0; j < 16; ++j) {
        int p = j * 256 + t;
        px[j] = pb[p * 3 + 0];
        py[j] = pb[p * 3 + 1];
        pz[j] = pb[p * 3 + 2];
    }
    int far;
    if (it0 == 0) {
        #pragma unroll
        for (int j = 0; j < 16; ++j) d[j] = 1e10f;
        far = 0;
    } else {
        #pragma unroll
        for (int j = 0; j < 16; ++j) d[j] = dws[b * 4096 + j * 256 + t];
        far = farws[b];
    }
    for (int it = it0; it < it1; ++it) {
        const int par = it & 1;
        if (t == 0) { inds_i[it] = far; inds_f[it] = (float)far; }
        const float cx = pb[far * 3 + 0];
        const float cy = pb[far * 3 + 1];
        const float cz = pb[far * 3 + 2];
        d[0] = fminf(d[0], dist2e(px[0], py[0], pz[0], cx, cy, cz));
        unsigned long long best = packdi(d[0], t);
        #pragma unroll
        for (int j = 1; j < 16; ++j) {
            d[j] = fminf(d[j], dist2e(px[j], py[j], pz[j], cx, cy, cz));
            unsigned long long c = packdi(d[j], j * 256 + t);
            if (c > best) best = c;
        }
        const unsigned hi = (unsigned)(best >> 32);
        const unsigned lo = (unsigned)(best & 0xFFFFFFFFull);
        float m = __uint_as_float(hi);
        m = dpp_maxf<0x111>(m);
        m = dpp_maxf<0x112>(m);
        m = dpp_maxf<0x114>(m);
        m = dpp_maxf<0x118>(m);
        m = dpp_maxf<0x142>(m);
        m = dpp_maxf<0x143>(m);
        const unsigned mbits = (unsigned)__builtin_amdgcn_readlane(__float_as_int(m), 63);
        unsigned cand = (hi == mbits) ? lo : 0u;
        cand = dpp_maxu<0x111>(cand);
        cand = dpp_maxu<0x112>(cand);
        cand = dpp_maxu<0x114>(cand);
        cand = dpp_maxu<0x118>(cand);
        cand = dpp_maxu<0x142>(cand);
        cand = dpp_maxu<0x143>(cand);
        const unsigned wlo = (unsigned)__builtin_amdgcn_readlane((int)cand, 63);
        if (lane == 0)
            s_red[par][wid] = ((unsigned long long)mbits << 32) | (unsigned long long)wlo;
        __syncthreads();
        unsigned long long mm = s_red[par][0];
        if (s_red[par][1] > mm) mm = s_red[par][1];
        if (s_red[par][2] > mm) mm = s_red[par][2];
        if (s_red[par][3] > mm) mm = s_red[par][3];
        far = (int)(0xFFFFFFFFu - (unsigned)(mm & 0xFFFFFFFFull));
    }
    if (it1 < 256) {
        #pragma unroll
        for (int j = 0; j < 16; ++j) dws[b * 4096 + j * 256 + t] = d[j];
        if (t == 0) farws[b] = far;
    }
}

// ---------------- split-bf16 MFMA FFN GEMM (+ FPS carrier) -------------------
// R6 structure (single staging bank, ZERO extra registers) + raw barriers:
// no vmcnt(0) drain at barriers, so the prefetch issued each phase stays in
// flight until first use (compiler per-register vmcnt), not force-drained.
// B1 = plain s_barrier (prior ds_reads consumed by pre-barrier MFMAs);
// B2 = lgkmcnt(0) + s_barrier (ds_write visibility only).
template <bool PRE_BN, bool STATS>
__global__ __launch_bounds__(256, 4)
void fgemm_k(const float* __restrict__ X,
             const unsigned short* __restrict__ Wh,
             const unsigned short* __restrict__ Wl,
             const float* __restrict__ bias,
             const float* __restrict__ scl, const float* __restrict__ sft,
             float* __restrict__ Y,
             float* __restrict__ psum, float* __restrict__ psqr,
             const float* __restrict__ xyz, int* __restrict__ sinds,
             float* __restrict__ inds_f, float* __restrict__ fpsd,
             int* __restrict__ fpsfar, int it0, int it1) {
    __shared__ __align__(16) unsigned short sBh[128 * 64];
    __shared__ __align__(16) unsigned short sBl[128 * 64];
    if (blockIdx.x < 16) {
        fps_seg(xyz, blockIdx.x, it0, it1, sinds + blockIdx.x * 256,
                inds_f + blockIdx.x * 256, fpsd, fpsfar, (char*)sBh);
        return;
    }
    int idx = blockIdx.x - 16;
    idx = (idx & 7) * 128 + (idx >> 3);
    const int b = idx >> 6, rem = idx & 63;
    const int nt = rem >> 1;
    const int n0 = nt * 128, o0 = (rem & 1) * 128;
    const int t = threadIdx.x;
    const int w = t >> 6, lane = t & 63;
    const int wm = (w >> 1) * 64, wn = (w & 1) * 64;
    const int lr = lane & 15, lk = lane >> 4;
    char* cBh = (char*)sBh;
    char* cBl = (char*)sBl;

    v4f acc[4][4];
    v4f zz = {0.f, 0.f, 0.f, 0.f};
    #pragma unroll
    for (int i = 0; i < 4; ++i)
        #pragma unroll
        for (int j = 0; j < 4; ++j) acc[i][j] = zz;

    const size_t aoff = (size_t)(o0 + wm + lr) * 256 + lk * 8;
    const unsigned short* pah = Wh + aoff;
    const unsigned short* pal = Wl + aoff;

    const int cblk = t >> 5, nq = t & 31;
    const float* xb = X + ((size_t)b * 256 + cblk * 8) * 4096 + n0 + nq * 4;

    v4f cur[8];
    #pragma unroll
    for (int i = 0; i < 8; ++i)
        cur[i] = *(const v4f*)(xb + (size_t)i * 4096);
    if (PRE_BN) bn8(cur, scl, sft, cblk * 8);

    #pragma unroll
    for (int ks = 0; ks < 4; ++ks) {
        const int k0 = ks * 64;
        // B1: LDS-overwrite guard only; no vmem/lgkm drain attached.
        __builtin_amdgcn_s_barrier();
        #pragma unroll
        for (int j = 0; j < 4; ++j) {
            const int n = nq * 4 + j;
            uint2 p0 = split2(cur[0][j], cur[1][j]);
            uint2 p1 = split2(cur[2][j], cur[3][j]);
            uint2 p2 = split2(cur[4][j], cur[5][j]);
            uint2 p3 = split2(cur[6][j], cur[7][j]);
            uint4 hh, ll;
            hh.x = p0.x; hh.y = p1.x; hh.z = p2.x; hh.w = p3.x;
            ll.x = p0.y; ll.y = p1.y; ll.z = p2.y; ll.w = p3.y;
            const int ad = n * 128 + ((cblk * 16) ^ ((n & 7) << 4));
            *(uint4*)(cBh + ad) = hh;
            *(uint4*)(cBl + ad) = ll;
        }
        // B2: my ds_writes visible to all waves; vmem loads left in flight.
        asm volatile("s_waitcnt lgkmcnt(0)" ::: "memory");
        __builtin_amdgcn_s_barrier();
        // prefetch next tile: stays in flight through the MFMA phase AND the
        // next iteration's barriers, until split2's first use of cur.
        if (ks < 3) {
            #pragma unroll
            for (int i = 0; i < 8; ++i)
                cur[i] = *(const v4f*)(xb + (size_t)(k0 + 64 + i) * 4096);
            if (PRE_BN) bn8(cur, scl, sft, k0 + 64 + cblk * 8);
        }
        #pragma unroll
        for (int kb = 0; kb < 2; ++kb) {
            const int koff = kb * 64 + lk * 16;
            const int ka = k0 + kb * 32;
            v8s ahf[4], alf[4], bhf[4], blf[4];
            #pragma unroll
            for (int f = 0; f < 4; ++f) {
                ahf[f] = *(const v8s*)(pah + (size_t)f * 4096 + ka);
                alf[f] = *(const v8s*)(pal + (size_t)f * 4096 + ka);
                const int rn = wn + f * 16 + lr;
                const int bm = rn * 128 + (koff ^ ((rn & 7) << 4));
                bhf[f] = *(const v8s*)(cBh + bm);
                blf[f] = *(const v8s*)(cBl + bm);
            }
            #pragma unroll
            for (int fm = 0; fm < 4; ++fm)
                #pragma unroll
                for (int fn = 0; fn < 4; ++fn) {
                    acc[fm][fn] = __builtin_amdgcn_mfma_f32_16x16x32_bf16(
                        ahf[fm], bhf[fn], acc[fm][fn], 0, 0, 0);
                    acc[fm][fn] = __builtin_amdgcn_mfma_f32_16x16x32_bf16(
                        ahf[fm], blf[fn], acc[fm][fn], 0, 0, 0);
                    acc[fm][fn] = __builtin_amdgcn_mfma_f32_16x16x32_bf16(
                        alf[fm], bhf[fn], acc[fm][fn], 0, 0, 0);
                }
        }
    }

    float* Yb = Y + (size_t)b * 256 * 4096;
    const int gnt = b * 32 + nt;
    #pragma unroll
    for (int fm = 0; fm < 4; ++fm) {
        const int obase = o0 + wm + fm * 16 + lk * 4;
        float bv[4];
        #pragma unroll
        for (int j = 0; j < 4; ++j) bv[j] = bias[obase + j];
        float ssr[4] = {0.f, 0.f, 0.f, 0.f}, qqr[4] = {0.f, 0.f, 0.f, 0.f};
        #pragma unroll
        for (int fn = 0; fn < 4; ++fn) {
            const int gn = n0 + wn + fn * 16 + lr;
            #pragma unroll
            for (int j = 0; j < 4; ++j) {
                const float yv = acc[fm][fn][j] + bv[j];
                Yb[(size_t)(obase + j) * 4096 + gn] = yv;
                ssr[j] += yv; qqr[j] += yv * yv;
            }
        }
        if (STATS) {
            #pragma unroll
            for (int j = 0; j < 4; ++j) {
                #pragma unroll
                for (int off = 1; off < 16; off <<= 1) {
                    ssr[j] += __shfl_xor(ssr[j], off, 64);
                    qqr[j] += __shfl_xor(qqr[j], off, 64);
                }
            }
            if (lr == 0) {
                const int col = gnt * 2 + (w & 1);
                #pragma unroll
                for (int j = 0; j < 4; ++j) {
                    psum[(size_t)(obase + j) * 1024 + col] = ssr[j];
                    psqr[(size_t)(obase + j) * 1024 + col] = qqr[j];
                }
            }
        }
    }
}

// ---------------- FFN weight split preconvert (hi/lo bf16 planes) -------------
__global__ __launch_bounds__(256)
void prepw_k(const float* __restrict__ W1, const float* __restrict__ W2,
             const float* __restrict__ W3, unsigned short* __restrict__ h1,
             unsigned short* __restrict__ l1, unsigned short* __restrict__ h2,
             unsigned short* __restrict__ l2, unsigned short* __restrict__ h3,
             unsigned short* __restrict__ l3) {
    const int o = blockIdx.x & 255, which = blockIdx.x >> 8, t = threadIdx.x;
    float v;
    unsigned short* ph;
    unsigned short* pl;
    if (which == 0) { v = W1[(size_t)o * 256 + t]; ph = h1; pl = l1; }
    else if (which == 1) { v = W2[(size_t)o * 256 + t]; ph = h2; pl = l2; }
    else { v = W3[(size_t)(o + 3) * 256 + t]; ph = h3; pl = l3; }  // rows 3..258
    unsigned short hu = f2bf(v);
    float rv = v - __uint_as_float((unsigned)hu << 16);
    ph[o * 256 + t] = hu;
    pl[o * 256 + t] = f2bf(rv);
}

// ---------------- BN finalize: npart partials -> scale/shift ------------------
__global__ __launch_bounds__(64)
void fin_k(const float* __restrict__ psum, const float* __restrict__ psqr,
           const float* __restrict__ g, const float* __restrict__ be,
           float* __restrict__ scl, float* __restrict__ sft, int npart) {
    const int c = blockIdx.x, t = threadIdx.x;
    const float4* ps = (const float4*)(psum + (size_t)c * 1024);
    const float4* pq = (const float4*)(psqr + (size_t)c * 1024);
    float s = 0.f, q = 0.f;
    for (int r = t; r < (npart >> 2); r += 64) {
        float4 a = ps[r]; s += a.x + a.y + a.z + a.w;
        float4 b2 = pq[r]; q += b2.x + b2.y + b2.z + b2.w;
    }
    #pragma unroll
    for (int sh = 32; sh; sh >>= 1) {
        s += __shfl_down(s, (unsigned)sh, 64);
        q += __shfl_down(q, (unsigned)sh, 64);
    }
    if (t == 0) {
        float mean = s * (1.f / 65536.f);
        float var = q * (1.f / 65536.f) - mean * mean;
        float sc = g[c] / sqrtf(var + 1e-5f);
        scl[c] = sc;
        sft[c] = be[c] - mean * sc;
    }
}

// ---------------- weight preconvert to bf16 (permuted mW1) --------------------
__global__ __launch_bounds__(256)
void prep_k(const float* __restrict__ mW1, const float* __restrict__ mW2,
            const float* __restrict__ mW3, unsigned short* __restrict__ W1p,
            unsigned short* __restrict__ W2p, unsigned short* __restrict__ W3p) {
    const int o = blockIdx.x & 255, which = blockIdx.x >> 8, t = threadIdx.x;
    if (which == 0) {
        W1p[o * 320 + t] = f2bf(mW1[o * 259 + 3 + t]);
        if (t < 64) {
            float v = (t < 3) ? mW1[o * 259 + t] : 0.f;
            W1p[o * 320 + 256 + t] = f2bf(v);
        }
    } else if (which == 1) {
        W2p[o * 256 + t] = f2bf(mW2[o * 256 + t]);
    } else {
        W3p[o * 256 + t] = f2bf(mW3[o * 256 + t]);
    }
}

// ---------------- vote_xyz (exact f32 coord dots) + normalized featT (bf16) ---
// Vectorized loads: each thread covers 4 n x 1 c, 8 channel passes.
// carries FPS segment 4 (blocks 0..15)
__global__ __launch_bounds__(256)
void votefeat_k(const float* __restrict__ OUT, const float* __restrict__ Y2,
                const float* __restrict__ xyz, const float* __restrict__ feats,
                const float* __restrict__ scl2, const float* __restrict__ sft2,
                const float* __restrict__ W3, const float* __restrict__ b3,
                float* __restrict__ vote_out, float* __restrict__ xyz_out,
                unsigned short* __restrict__ featT,
                int* __restrict__ sinds, float* __restrict__ inds_f,
                float* __restrict__ fpsd, int* __restrict__ fpsfar,
                int it0, int it1) {
    __shared__ float tile[32 * 257];
    __shared__ float ssb[32][33];
    __shared__ float rn[32];
    __shared__ float sW3[768];
    __shared__ float dred[3][32][33];
    if (blockIdx.x < 16) {
        fps_seg(xyz, blockIdx.x, it0, it1, sinds + blockIdx.x * 256,
                inds_f + blockIdx.x * 256, fpsd, fpsfar, (char*)tile);
        return;
    }
    const int blk = blockIdx.x - 16;
    const int b = blk >> 7, n0 = (blk & 127) * 32;
    const int t = threadIdx.x;
    const int nl4 = (t & 7) * 4, sl = t >> 3;  // 4-n block, channel slice 0..31
    const float* Fb = feats + (size_t)b * 256 * NPT;
    const float* Ob = OUT + (size_t)b * 256 * NPT;
    const float* Yb = Y2 + (size_t)b * 256 * NPT;
    #pragma unroll
    for (int r = 0; r < 3; ++r) sW3[r * 256 + t] = W3[r * 256 + t];
    __syncthreads();
    float ss[4] = {0.f, 0.f, 0.f, 0.f};
    float dd[3][4];
    #pragma unroll
    for (int r = 0; r < 3; ++r)
        #pragma unroll
        for (int j = 0; j < 4; ++j) dd[r][j] = 0.f;
    #pragma unroll
    for (int ci = 0; ci < 8; ++ci) {
        const int c = ci * 32 + sl;
        const size_t coff = (size_t)c * NPT + n0 + nl4;
        const v4f f4 = *(const v4f*)(Fb + coff);
        const v4f o4 = *(const v4f*)(Ob + coff);
        const v4f y4 = *(const v4f*)(Yb + coff);
        const float s2 = scl2[c], sh2 = sft2[c];
        const float w0 = sW3[c], w1 = sW3[256 + c], w2 = sW3[512 + c];
        #pragma unroll
        for (int j = 0; j < 4; ++j) {
            const float v = f4[j] + o4[j];
            tile[(nl4 + j) * 257 + c] = v;
            ss[j] = fmaf(v, v, ss[j]);
            const float h = fmaxf(fmaf(y4[j], s2, sh2), 0.f);
            dd[0][j] = fmaf(h, w0, dd[0][j]);
            dd[1][j] = fmaf(h, w1, dd[1][j]);
            dd[2][j] = fmaf(h, w2, dd[2][j]);
        }
    }
    #pragma unroll
    for (int j = 0; j < 4; ++j) ssb[nl4 + j][sl] = ss[j];
    #pragma unroll
    for (int r = 0; r < 3; ++r)
        #pragma unroll
        for (int j = 0; j < 4; ++j) dred[r][nl4 + j][sl] = dd[r][j];
    __syncthreads();
    if (t < 32) {
        float s = 0.f;
        #pragma unroll
        for (int k = 0; k < 32; ++k) s += ssb[t][k];
        rn[t] = 1.0f / sqrtf(s);
    }
    __syncthreads();
    // featT: vectorized 8B stores (4 channels per thread per pass)
    #pragma unroll
    for (int pp = 0; pp < 8; ++pp) {
        const int p = pp * 4 + (t >> 6);
        const int ch = (t & 63) * 4;
        const float rv = rn[p];
        const float v0 = tile[p * 257 + ch + 0] * rv;
        const float v1 = tile[p * 257 + ch + 1] * rv;
        const float v2 = tile[p * 257 + ch + 2] * rv;
        const float v3 = tile[p * 257 + ch + 3] * rv;
        *(uint2*)&featT[((size_t)b * NPT + n0 + p) * 256 + ch] =
            make_uint2(pk2(v0, v1), pk2(v2, v3));
    }
    if (t < 96) {
        const int r = t >> 5, p = t & 31;
        float d = b3[r];
        #pragma unroll
        for (int k = 0; k < 32; ++k) d += dred[r][p][k];
        float sig = 1.f / (1.f + expf(-d));
        sig = fminf(fmaxf(sig, 0.1f), 0.9f);
        const size_t gi = ((size_t)b * NPT + n0 + p) * 3 + r;
        const float e = xyz[gi];
        vote_out[gi] = e + sig - 0.5f;
        xyz_out[gi] = e;
    }
}

// ---------------- ball query: one wave per (b,q) ------------------------------
__global__ __launch_bounds__(64)
void bq_k(const float* __restrict__ vote, const int* __restrict__ sinds,
          float* __restrict__ qxyz_out, int* __restrict__ idx_out) {
    const int bq = blockIdx.x;
    const int b = bq >> 8;
    const int lane = threadIdx.x;
    __shared__ int s_idx[16];
    const int si = sinds[bq];
    const float* vb = vote + (size_t)b * NPT * 3;
    const float qx = vb[si * 3 + 0], qy = vb[si * 3 + 1], qz = vb[si * 3 + 2];
    if (lane < 3) qxyz_out[bq * 3 + lane] = vb[si * 3 + lane];
    int cnt = 0;
    for (int cb = 0; cb < 64 && cnt < 16; ++cb) {
        int n = cb * 64 + lane;
        float x = vb[n * 3], y = vb[n * 3 + 1], z = vb[n * 3 + 2];
        float d2 = dist2e(x, y, z, qx, qy, qz);
        unsigned long long m = __ballot(d2 < 0.09f);
        while (m && cnt < 16) {
            int bit = __builtin_ctzll(m);
            s_idx[cnt] = cb * 64 + bit;
            ++cnt;
            m &= m - 1;
        }
    }
    __syncthreads();
    if (lane < 16) {
        int v = (lane < cnt) ? s_idx[lane] : (cnt > 0 ? s_idx[0] : 0);
        idx_out[bq * 16 + lane] = v;
    }
}

// ---------------- grouping: build G^T bf16 [65536][320] (permuted cols) -------
__global__ __launch_bounds__(256)
void group_k(const unsigned short* __restrict__ featT, const float* __restrict__ vote,
             const float* __restrict__ qxyz, const int* __restrict__ idxs,
             unsigned short* __restrict__ Gt) {
    const int bq = blockIdx.x;
    const int b = bq >> 8, q = bq & 255;
    const int t = threadIdx.x;
    __shared__ int s_i[16];
    __shared__ float s_q[3];
    if (t < 16) s_i[t] = idxs[bq * 16 + t];
    if (t < 3) s_q[t] = qxyz[bq * 3 + t];
    __syncthreads();
    const int s = t >> 4, part = t & 15;
    const int i = s_i[s];
    const size_t nrow = (size_t)b * 4096 + q * 16 + s;
    const uint4* src = (const uint4*)(featT + ((size_t)b * NPT + i) * 256 + part * 16);
    uint4* dst = (uint4*)(Gt + nrow * 320 + part * 16);
    dst[0] = src[0];
    dst[1] = src[1];
    for (int c = 259 + part; c < 320; c += 16) Gt[nrow * 320 + c] = 0;
    if (part < 3) {
        float v = (vote[((size_t)b * NPT + i) * 3 + part] - s_q[part]) * (1.f / 0.3f);
        Gt[nrow * 320 + 256 + part] = f2bf(v);
    }
}

// ---------------- bf16 MFMA GEMM: Y^T[n][o] = sum_k W[o][k] X^T[n][k] ---------
// A (weights) read direct from global (L2-hot, shared by all blocks);
// only B staged in LDS (16 KB) -> 4 blocks/CU. Raw barriers (no vmem drain).
__device__ __forceinline__ unsigned bnpair(unsigned u, float sl, float sh,
                                           float fl, float fh) {
    float lo = __uint_as_float(u << 16);
    float hi = __uint_as_float(u & 0xFFFF0000u);
    lo = fmaxf(fmaf(lo, sl, fl), 0.f);
    hi = fmaxf(fmaf(hi, sh, fh), 0.f);
    unsigned r;
    asm("v_cvt_pk_bf16_f32 %0, %1, %2" : "=v"(r) : "v"(lo), "v"(hi));
    return r;
}

template <int KPAD, bool BNSTAGE, bool EPIMAX>
__global__ __launch_bounds__(256, 4)
void mgemm_k(const unsigned short* __restrict__ Wb,
             const unsigned short* __restrict__ Xt,
             const float* __restrict__ bias,
             const float* __restrict__ scl, const float* __restrict__ sft,
             unsigned short* __restrict__ Yt, float* __restrict__ rmax,
             float* __restrict__ psum, float* __restrict__ psqr) {
    __shared__ __align__(16) unsigned short sB[128 * 64];
    char* cB = (char*)sB;
    const int t = threadIdx.x;
    const int n0 = blockIdx.x * 128, o0 = blockIdx.y * 128;
    const int w = t >> 6, lane = t & 63;
    const int wm = (w >> 1) * 64, wn = (w & 1) * 64;
    const int lr = lane & 15, lk = lane >> 4;

    v4f acc[4][4];
    v4f zz = {0.f, 0.f, 0.f, 0.f};
    #pragma unroll
    for (int i = 0; i < 4; ++i)
        #pragma unroll
        for (int j = 0; j < 4; ++j) acc[i][j] = zz;

    // A direct-from-global base (per-thread)
    const unsigned short* pa = Wb + (size_t)(o0 + wm + lr) * KPAD + lk * 8;

    const int ra = t >> 1, kc = (t & 1) * 32;
    const unsigned short* bsrc = Xt + (size_t)(n0 + ra) * KPAD + kc;
    constexpr int nk = KPAD / 64;

    // prologue: B tile 0 -> regs (+BN)
    uint4 bv[4];
    #pragma unroll
    for (int i = 0; i < 4; ++i) bv[i] = *(const uint4*)(bsrc + 8 * i);
    if constexpr (BNSTAGE) {
        #pragma unroll
        for (int i = 0; i < 4; ++i) {
            const int kk = kc + 8 * i;
            float4 s0 = *(const float4*)(scl + kk);
            float4 s1 = *(const float4*)(scl + kk + 4);
            float4 f0 = *(const float4*)(sft + kk);
            float4 f1 = *(const float4*)(sft + kk + 4);
            bv[i].x = bnpair(bv[i].x, s0.x, s0.y, f0.x, f0.y);
            bv[i].y = bnpair(bv[i].y, s0.z, s0.w, f0.z, f0.w);
            bv[i].z = bnpair(bv[i].z, s1.x, s1.y, f1.x, f1.y);
            bv[i].w = bnpair(bv[i].w, s1.z, s1.w, f1.z, f1.w);
        }
    }

    #pragma unroll
    for (int ks = 0; ks < nk; ++ks) {
        // B1: LDS-overwrite guard only.
        __builtin_amdgcn_s_barrier();
        #pragma unroll
        for (int i = 0; i < 4; ++i) {
            const int kb2 = (kc + 8 * i) * 2;
            *(uint4*)(cB + ra * 128 + (kb2 ^ ((ra & 7) << 4))) = bv[i];
        }
        // B2: ds_write visibility; vmem loads left in flight.
        asm volatile("s_waitcnt lgkmcnt(0)" ::: "memory");
        __builtin_amdgcn_s_barrier();
        // prefetch next B K-tile (in flight until next iteration's ds_write)
        if (ks + 1 < nk) {
            const int k1 = (ks + 1) * 64;
            #pragma unroll
            for (int i = 0; i < 4; ++i) bv[i] = *(const uint4*)(bsrc + k1 + 8 * i);
            if constexpr (BNSTAGE) {
                #pragma unroll
                for (int i = 0; i < 4; ++i) {
                    const int kk = k1 + kc + 8 * i;
                    float4 s0 = *(const float4*)(scl + kk);
                    float4 s1 = *(const float4*)(scl + kk + 4);
                    float4 f0 = *(const float4*)(sft + kk);
                    float4 f1 = *(const float4*)(sft + kk + 4);
                    bv[i].x = bnpair(bv[i].x, s0.x, s0.y, f0.x, f0.y);
                    bv[i].y = bnpair(bv[i].y, s0.z, s0.w, f0.z, f0.w);
                    bv[i].z = bnpair(bv[i].z, s1.x, s1.y, f1.x, f1.y);
                    bv[i].w = bnpair(bv[i].w, s1.z, s1.w, f1.z, f1.w);
                }
            }
        }
        #pragma unroll
        for (int kb = 0; kb < 2; ++kb) {
            const int koff = (kb * 32 + lk * 8) * 2;
            const int ka = ks * 64 + kb * 32;
            v8s af[4], bf[4];
            #pragma unroll
            for (int f = 0; f < 4; ++f) {
                af[f] = *(const v8s*)(pa + (size_t)(f * 16) * KPAD + ka);
                const int rn = wn + f * 16 + lr;
                bf[f] = *(const v8s*)(cB + rn * 128 + (koff ^ ((rn & 7) << 4)));
            }
            #pragma unroll
            for (int fm = 0; fm < 4; ++fm)
                #pragma unroll
                for (int fn = 0; fn < 4; ++fn)
                    acc[fm][fn] = __builtin_amdgcn_mfma_f32_16x16x32_bf16(
                        af[fm], bf[fn], acc[fm][fn], 0, 0, 0);
        }
    }

    // epilogue: bias, (Y-write | q-max), BN partial stats
    const int bx = blockIdx.x;
    #pragma unroll
    for (int fm = 0; fm < 4; ++fm) {
        const int obase = o0 + wm + fm * 16 + lk * 4;
        const float4 bv4 = *(const float4*)(bias + obase);
        float s0 = 0.f, s1 = 0.f, s2 = 0.f, s3 = 0.f;
        float q0 = 0.f, q1 = 0.f, q2 = 0.f, q3 = 0.f;
        #pragma unroll
        for (int fn = 0; fn < 4; ++fn) {
            float y0 = acc[fm][fn][0] + bv4.x;
            float y1 = acc[fm][fn][1] + bv4.y;
            float y2 = acc[fm][fn][2] + bv4.z;
            float y3 = acc[fm][fn][3] + bv4.w;
            s0 += y0; s1 += y1; s2 += y2; s3 += y3;
            q0 += y0 * y0; q1 += y1 * y1; q2 += y2 * y2; q3 += y3 * y3;
            if constexpr (!EPIMAX) {
                unsigned p0, p1;
                asm("v_cvt_pk_bf16_f32 %0, %1, %2" : "=v"(p0) : "v"(y0), "v"(y1));
                asm("v_cvt_pk_bf16_f32 %0, %1, %2" : "=v"(p1) : "v"(y2), "v"(y3));
                const int gn = n0 + wn + fn * 16 + lr;
                *(uint2*)(Yt + (size_t)gn * 256 + obase) = make_uint2(p0, p1);
            } else {
                float m0 = y0, m1 = y1, m2 = y2, m3 = y3;
                #pragma unroll
                for (int off = 1; off < 16; off <<= 1) {
                    m0 = fmaxf(m0, __shfl_xor(m0, off, 64));
                    m1 = fmaxf(m1, __shfl_xor(m1, off, 64));
                    m2 = fmaxf(m2, __shfl_xor(m2, off, 64));
                    m3 = fmaxf(m3, __shfl_xor(m3, off, 64));
                }
                if (lr == 0) {
                    const int gq = (n0 + wn + fn * 16) >> 4;
                    const int bb = gq >> 8, qq = gq & 255;
                    float* rp = rmax + ((size_t)bb * 256 + obase) * 256 + qq;
                    rp[0] = m0; rp[256] = m1; rp[512] = m2; rp[768] = m3;
                }
            }
        }
        #pragma unroll
        for (int off = 1; off < 16; off <<= 1) {
            s0 += __shfl_xor(s0, off, 64); q0 += __shfl_xor(q0, off, 64);
            s1 += __shfl_xor(s1, off, 64); q1 += __shfl_xor(q1, off, 64);
            s2 += __shfl_xor(s2, off, 64); q2 += __shfl_xor(q2, off, 64);
            s3 += __shfl_xor(s3, off, 64); q3 += __shfl_xor(q3, off, 64);
        }
        if (lr == 0) {
            const int col = bx * 2 + (w & 1);
            psum[(size_t)(obase + 0) * 1024 + col] = s0;
            psum[(size_t)(obase + 1) * 1024 + col] = s1;
            psum[(size_t)(obase + 2) * 1024 + col] = s2;
            psum[(size_t)(obase + 3) * 1024 + col] = s3;
            psqr[(size_t)(obase + 0) * 1024 + col] = q0;
            psqr[(size_t)(obase + 1) * 1024 + col] = q1;
            psqr[(size_t)(obase + 2) * 1024 + col] = q2;
            psqr[(size_t)(obase + 3) * 1024 + col] = q3;
        }
    }
}

// ---------------- final: qf = relu(sc*rawmax + sh) ----------------------------
__global__ __launch_bounds__(256)
void qf_k(const float* __restrict__ rmax, const float* __restrict__ scl,
          const float* __restrict__ sft, float* __restrict__ out) {
    const int g = blockIdx.x * 256 + threadIdx.x;
    const int c = (g >> 8) & 255;
    out[g] = fmaxf(fmaf(rmax[g], scl[c], sft[c]), 0.f);
}

extern "C" void kernel_launch(void* const* d_in, const int* in_sizes, int n_in,
                              void* d_out, int out_size, void* d_ws, size_t ws_size,
                              hipStream_t stream) {
    const float* xyz   = (const float*)d_in[0];
    const float* feats = (const float*)d_in[1];
    const float* W1 = (const float*)d_in[2];
    const float* b1 = (const float*)d_in[3];
    const float* g1 = (const float*)d_in[4];
    const float* be1 = (const float*)d_in[5];
    const float* W2 = (const float*)d_in[6];
    const float* b2 = (const float*)d_in[7];
    const float* g2 = (const float*)d_in[8];
    const float* be2 = (const float*)d_in[9];
    const float* W3 = (const float*)d_in[10];
    const float* b3 = (const float*)d_in[11];
    const float* mW1 = (const float*)d_in[12];
    const float* mb1 = (const float*)d_in[13];
    const float* mg1 = (const float*)d_in[14];
    const float* mbe1 = (const float*)d_in[15];
    const float* mW2 = (const float*)d_in[16];
    const float* mb2 = (const float*)d_in[17];
    const float* mg2 = (const float*)d_in[18];
    const float* mbe2 = (const float*)d_in[19];
    const float* mW3 = (const float*)d_in[20];
    const float* mb3 = (const float*)d_in[21];
    const float* mg3 = (const float*)d_in[22];
    const float* mbe3 = (const float*)d_in[23];

    float* out_vote = (float*)d_out;
    float* out_xyz = out_vote + 196608;
    float* out_inds = out_xyz + 196608;
    float* out_q = out_inds + 4096;
    float* out_qf = out_q + 12288;

    // ws layout (floats) — unchanged footprint
    float* ws = (float*)d_ws;
    float* A      = ws;                      // 16973824 f : y1 -> OUT -> Gt(bf16)
    float* Bb     = A + 16973824;            // 16777216 f : y2 -> Y1t(bf16)
    float* Ft     = Bb + 16777216;           // 8388608 f  : featT(bf16) -> Y2t(bf16)
    float* rawmax = Ft + 8388608;            // 1048576 f (front reused for W planes)
    float* psum   = rawmax + 1048576;        // 262144
    float* psqr   = psum + 262144;           // 262144
    float* st     = psqr + 262144;           // 2560
    float* fpsd   = st + 2560;               // 65536
    float* wbase  = fpsd + 65536;
    unsigned short* Wb1 = (unsigned short*)wbase;           // 81920 h
    unsigned short* Wb2 = Wb1 + 81920;                      // 65536 h
    unsigned short* Wb3 = Wb2 + 65536;                      // 65536 h
    int* sinds  = (int*)(Wb3 + 65536);
    int* bidx   = sinds + 4096;
    int* fpsfar = bidx + 65536;

    unsigned short* Gt  = (unsigned short*)A;
    unsigned short* Y1t = (unsigned short*)Bb;
    unsigned short* featT = (unsigned short*)Ft;
    unsigned short* Y2t = (unsigned short*)Ft;

    // FFN split-bf16 weight planes: carved from rawmax region (dead until mgemm3)
    unsigned short* Wf1h = (unsigned short*)rawmax;
    unsigned short* Wf1l = Wf1h + 65536;
    unsigned short* Wf2h = Wf1l + 65536;
    unsigned short* Wf2l = Wf2h + 65536;
    unsigned short* Wf3h = Wf2l + 65536;
    unsigned short* Wf3l = Wf3h + 65536;     // total 393216 h = 196608 f < 1048576

    prep_k<<<768, 256, 0, stream>>>(mW1, mW2, mW3, Wb1, Wb2, Wb3);
    prepw_k<<<768, 256, 0, stream>>>(W1, W2, W3, Wf1h, Wf1l, Wf2h, Wf2l, Wf3h, Wf3l);

    // FFN as split-bf16 MFMA GEMMs; FPS split into 4x64-iter hidden segments
    fgemm_k<false, true><<<1040, 256, 0, stream>>>(
        feats, Wf1h, Wf1l, b1, nullptr, nullptr, A, psum, psqr,
        xyz, sinds, out_inds, fpsd, fpsfar, 0, 64);
    fin_k<<<256, 64, 0, stream>>>(psum, psqr, g1, be1, st + 0, st + 256, 1024);
    fgemm_k<true, true><<<1040, 256, 0, stream>>>(
        A, Wf2h, Wf2l, b2, st + 0, st + 256, Bb, psum, psqr,
        xyz, sinds, out_inds, fpsd, fpsfar, 64, 128);
    fin_k<<<256, 64, 0, stream>>>(psum, psqr, g2, be2, st + 512, st + 768, 1024);
    // GEMM3: only the 256 feature-delta rows (W3 rows 3..258); coord rows 0..2
    // are computed exactly in f32 inside votefeat_k from y2 (Bb).
    fgemm_k<true, false><<<1040, 256, 0, stream>>>(
        Bb, Wf3h, Wf3l, b3 + 3, st + 512, st + 768, A, nullptr, nullptr,
        xyz, sinds, out_inds, fpsd, fpsfar, 128, 192);

    votefeat_k<<<2064, 256, 0, stream>>>(A, Bb, xyz, feats, st + 512, st + 768,
                                         W3, b3, out_vote, out_xyz, featT,
                                         sinds, out_inds, fpsd, fpsfar, 192, 256);
    bq_k<<<4096, 64, 0, stream>>>(out_vote, sinds, out_q, bidx);
    group_k<<<4096, 256, 0, stream>>>(featT, out_vote, out_q, bidx, Gt);

    // SA MLP: bf16 MFMA GEMMs (A-direct, 4 blocks/CU, raw barriers)
    mgemm_k<320, false, false><<<dim3(512, 2), 256, 0, stream>>>(
        Wb1, Gt, mb1, nullptr, nullptr, Y1t, nullptr, psum, psqr);
    fin_k<<<256, 64, 0, stream>>>(psum, psqr, mg1, mbe1, st + 1024, st + 1280, 1024);
    mgemm_k<256, true, false><<<dim3(512, 2), 256, 0, stream>>>(
        Wb2, Y1t, mb2, st + 1024, st + 1280, Y2t, nullptr, psum, psqr);
    fin_k<<<256, 64, 0, stream>>>(psum, psqr, mg2, mbe2, st + 1536, st + 1792, 1024);
    mgemm_k<256, true, true><<<dim3(512, 2), 256, 0, stream>>>(
        Wb3, Y2t, mb3, st + 1536, st + 1792, nullptr, rawmax, psum, psqr);
    fin_k<<<256, 64, 0, stream>>>(psum, psqr, mg3, mbe3, st + 2048, st + 2304, 1024);
    qf_k<<<4096, 256, 0, stream>>>(rawmax, st + 2048, st + 2304, out_qf);
}